// Round 8
// baseline (490.286 us; speedup 1.0000x reference)
//
#include <hip/hip_runtime.h>
#include <hip/hip_bf16.h>
#include <stdint.h>

#define TWO_N  8192
#define NHALF  4096
#define DDIM   256
#define MARGIN 0.5f
#define NTRI   2080   // 64*65/2 upper-triangle tile pairs

// ---- workspace layout (bytes) ----
static const size_t OFF_EMB  = 0;                             // 8192*256 bf16 = 4 MB
static const size_t OFF_X2   = 4u * 1024 * 1024;              // 8192 f32 = 32 KB
static const size_t OFF_AP   = OFF_X2 + (size_t)TWO_N * 4;    // 4096 f32 = 16 KB
static const size_t OFF_FLAG = OFF_AP + (size_t)NHALF * 4;    // 1 int (padded)
static const size_t OFF_BITM = 5u * 1024 * 1024;              // 8192*1024 B = 8 MB bitmask
static const size_t OFF_RS   = 13u * 1024 * 1024;             // 8192 f32 = 32 KB

typedef __attribute__((ext_vector_type(8))) short bf16x8;
typedef __attribute__((ext_vector_type(4))) float f32x4;

__device__ inline ushort f2bf(float f) {
  uint32_t u = __float_as_uint(f);
  uint32_t r = (u + 0x7FFFu + ((u >> 16) & 1u)) >> 16;  // RNE
  return (ushort)r;
}
__device__ inline float bf2f(ushort h) { return __uint_as_float((uint32_t)h << 16); }

// async global->LDS; LDS dest = wave-uniform base + lane*size
__device__ inline void gload_lds4(const void* g, void* l) {
  __builtin_amdgcn_global_load_lds(
      (const __attribute__((address_space(1))) uint32_t*)(uintptr_t)g,
      (__attribute__((address_space(3))) uint32_t*)(uint32_t)(uintptr_t)l,
      4, 0, 0);
}

// ---------------- prep: bf16 convert + x2 (from bf16 values) + mask-dtype detect ----------------
__global__ __launch_bounds__(256) void smv2_prep(
    const float* __restrict__ emb,
    const uint32_t* __restrict__ maskw,
    ushort* __restrict__ emb_bf,
    float* __restrict__ x2,
    int* __restrict__ flag)
{
  const int t = threadIdx.x;
  if (blockIdx.x == 0) {
    __shared__ int sflag;
    if (t == 0) sflag = 0;
    __syncthreads();
    int found = 0;
    #pragma unroll
    for (int k = 0; k < 8; ++k) {
      uint32_t w = maskw[t * 8 + k];
      if (w > 1u && (w & 0xFEFEFEFEu) == 0u) found = 1;  // bytes in {0,1} => byte mask
    }
    if (found) atomicOr(&sflag, 1);
    __syncthreads();
    if (t == 0) *flag = sflag;
  }
  const int row  = blockIdx.x * 8 + (t >> 5);
  const int lane = t & 31;
  const float* rp = emb + (size_t)row * DDIM + lane * 8;
  float4 v0 = *(const float4*)(rp);
  float4 v1 = *(const float4*)(rp + 4);
  float vals[8] = {v0.x, v0.y, v0.z, v0.w, v1.x, v1.y, v1.z, v1.w};
  uint32_t packed[4];
  float ss = 0.f;
  #pragma unroll
  for (int k = 0; k < 4; ++k) {
    ushort h0 = f2bf(vals[2 * k]);
    ushort h1 = f2bf(vals[2 * k + 1]);
    packed[k] = (uint32_t)h0 | ((uint32_t)h1 << 16);
    float f0 = bf2f(h0), f1 = bf2f(h1);
    ss += f0 * f0 + f1 * f1;
  }
  *(uint4*)(emb_bf + (size_t)row * DDIM + lane * 8) =
      make_uint4(packed[0], packed[1], packed[2], packed[3]);
  #pragma unroll
  for (int m = 1; m < 32; m <<= 1) ss += __shfl_xor(ss, m);
  if (lane == 0) x2[row] = ss;
}

// ---------------- pack: mask (byte or word) -> bit mask (8192 x 1024 B rows); zero rs ------------
__global__ __launch_bounds__(256) void smv2_pack(
    const uint8_t* __restrict__ mask8,
    const int* __restrict__ flagp,
    uint32_t* __restrict__ bitM,
    float* __restrict__ rs)
{
  const int t = threadIdx.x;
  if (blockIdx.x == 0) {            // zero rs: 8192 f32 = 2048 float4
    float4 z = {0.f, 0.f, 0.f, 0.f};
    #pragma unroll
    for (int i = 0; i < 8; ++i) ((float4*)rs)[t * 8 + i] = z;
  }
  const int tid = blockIdx.x * 256 + t;
  const int isByte = *flagp;
  if (isByte) {
    #pragma unroll
    for (int it = 0; it < 4; ++it) {
      const int idx = it * (2048 * 256) + tid;   // u32 output index; 32 mask bytes
      const uint4 a = ((const uint4*)mask8)[(size_t)idx * 2];
      const uint4 b = ((const uint4*)mask8)[(size_t)idx * 2 + 1];
      const uint32_t wsv[8] = {a.x, a.y, a.z, a.w, b.x, b.y, b.z, b.w};
      uint32_t out = 0;
      #pragma unroll
      for (int j = 0; j < 8; ++j)
        out |= ((((wsv[j] & 0x01010101u) * 0x01020408u) >> 24) & 0xFu) << (4 * j);
      bitM[idx] = out;
    }
  } else {
    const uint32_t* maskw = (const uint32_t*)mask8;
    #pragma unroll
    for (int it = 0; it < 4; ++it) {
      const int idx = it * (2048 * 256) + tid;   // 32 mask words
      uint32_t out = 0;
      #pragma unroll
      for (int j = 0; j < 8; ++j) {
        const uint4 wv = ((const uint4*)maskw)[(size_t)idx * 8 + j];
        out |= (wv.x != 0u ? 1u : 0u) << (4 * j);
        out |= (wv.y != 0u ? 1u : 0u) << (4 * j + 1);
        out |= (wv.z != 0u ? 1u : 0u) << (4 * j + 2);
        out |= (wv.w != 0u ? 1u : 0u) << (4 * j + 3);
      }
      bitM[idx] = out;
    }
  }
}

// ---------------- main: symmetric fused Gram -> dist -> exp -> masked row+col partials ----------
// Upper-triangle tile pairs (by<=bx), 512 threads (8 waves 2x4), tile 128x128.
// emb_bf (4 MB) is L2/L3-resident: MFMA fragments load DIRECTLY from global into
// VGPRs — no A/B LDS, no staging barriers, waves free-run (common-mistake #7 fix).
// LDS: 2K bitmask tile + 1K x2 + 3K partials = 6 KB. Occupancy VGPR-bound.
__global__ __launch_bounds__(512, 6) void smv2_main(
    const ushort* __restrict__ emb_bf,
    const float* __restrict__ x2,
    const uint8_t* __restrict__ bitM,
    float* __restrict__ ap,
    float* __restrict__ rs)
{
  __shared__ uint32_t ldsM[512];       // 128 rows x 16 B bit-mask tile
  __shared__ float ldsX[256];          // x2[brow..+128) | x2[bcol..+128)
  __shared__ float part[512];          // [4][128] row-side partials
  __shared__ float part2[256];         // [2][128] col-side partials

  const int t = threadIdx.x;

  // XCD chunking (2080 = 8*260) + triangular decode (bx-outer: B panel stable per XCD)
  const int bid = blockIdx.x;
  const int idx = (bid & 7) * (NTRI / 8) + (bid >> 3);
  float rf = sqrtf(8.f * (float)idx + 1.f);
  int bx = (int)((rf - 1.f) * 0.5f);
  while ((bx + 1) * (bx + 2) / 2 <= idx) ++bx;
  while (bx * (bx + 1) / 2 > idx) --bx;
  const int by = idx - bx * (bx + 1) / 2;  // by <= bx
  const int brow = by * 128;
  const int bcol = bx * 128;
  const bool diag = (bx == by);

  const int w  = t >> 6;
  const int l  = t & 63;
  const int wr = w >> 2;           // wave row 0..1  (64 rows)
  const int wc = w & 3;            // wave col 0..3  (32 cols)
  const int cl = l & 15;
  const int kh = l >> 4;
  const int srow = t >> 2;         // 0..127 (staging row for M1)

  // ---- issue M1 bit tile (2 KB) + x2 slices (1 KB) into LDS (drained at the sync below) ----
  gload_lds4(bitM + (size_t)(brow + srow) * 1024 + (bcol >> 3) + (t & 3) * 4,
             (char*)ldsM + t * 4);
  {
    const int xi = t & 255;
    const float* src = (xi < 128) ? (x2 + brow + xi) : (x2 + bcol + (xi - 128));
    gload_lds4(src, (char*)ldsX + xi * 4);
  }
  // ---- M2 (mirror mask) to registers: 64 bits of row gj covering cols [brow+wr*64, +64) ----
  uint2 m2[2];
  #pragma unroll
  for (int n = 0; n < 2; ++n) {
    const int gj = bcol + wc * 32 + n * 16 + cl;
    m2[n] = *(const uint2*)(bitM + (size_t)gj * 1024 + (brow >> 3) + wr * 8);
  }

  // ---- per-lane fragment base pointers (512 B rows) ----
  const char* pA = (const char*)emb_bf + (size_t)(brow + wr * 64 + cl) * 512 + kh * 16;
  const char* pB = (const char*)emb_bf + (size_t)(bcol + wc * 32 + cl) * 512 + kh * 16;

  f32x4 acc[4][2];
  #pragma unroll
  for (int m = 0; m < 4; ++m)
    #pragma unroll
    for (int n = 0; n < 2; ++n) {
      f32x4 z = {0.f, 0.f, 0.f, 0.f};
      acc[m][n] = z;
    }

  // ---- K loop: 8 steps of K=32; fragments straight from L2; no barriers ----
  #pragma unroll
  for (int p = 0; p < 8; ++p) {
    bf16x8 a0 = *(const bf16x8*)(pA + 0 * 8192 + p * 64);
    bf16x8 a1 = *(const bf16x8*)(pA + 1 * 8192 + p * 64);
    bf16x8 a2 = *(const bf16x8*)(pA + 2 * 8192 + p * 64);
    bf16x8 a3 = *(const bf16x8*)(pA + 3 * 8192 + p * 64);
    bf16x8 b0 = *(const bf16x8*)(pB + 0 * 8192 + p * 64);
    bf16x8 b1 = *(const bf16x8*)(pB + 1 * 8192 + p * 64);
    acc[0][0] = __builtin_amdgcn_mfma_f32_16x16x32_bf16(a0, b0, acc[0][0], 0, 0, 0);
    acc[0][1] = __builtin_amdgcn_mfma_f32_16x16x32_bf16(a0, b1, acc[0][1], 0, 0, 0);
    acc[1][0] = __builtin_amdgcn_mfma_f32_16x16x32_bf16(a1, b0, acc[1][0], 0, 0, 0);
    acc[1][1] = __builtin_amdgcn_mfma_f32_16x16x32_bf16(a1, b1, acc[1][1], 0, 0, 0);
    acc[2][0] = __builtin_amdgcn_mfma_f32_16x16x32_bf16(a2, b0, acc[2][0], 0, 0, 0);
    acc[2][1] = __builtin_amdgcn_mfma_f32_16x16x32_bf16(a2, b1, acc[2][1], 0, 0, 0);
    acc[3][0] = __builtin_amdgcn_mfma_f32_16x16x32_bf16(a3, b0, acc[3][0], 0, 0, 0);
    acc[3][1] = __builtin_amdgcn_mfma_f32_16x16x32_bf16(a3, b1, acc[3][1], 0, 0, 0);
  }

  __syncthreads();   // drains M1/x2 gload_lds; LDS now valid for the epilogue

  float cs[2] = {0.f, 0.f};

  #pragma unroll
  for (int m = 0; m < 4; ++m) {
    #pragma unroll
    for (int q = 0; q < 4; ++q) {
      const int lrow = wr * 64 + m * 16 + kh * 4 + q;  // C/D: row = (l>>4)*4 + reg
      const int gi = brow + lrow;
      const float xi = ldsX[lrow];
      const uint32_t m1w = ldsM[lrow * 4 + wc];        // bits for cols [wc*32, +32)
      float rp = 0.f;
      #pragma unroll
      for (int n = 0; n < 2; ++n) {
        const int jc = wc * 32 + n * 16 + cl;
        const int gj = bcol + jc;
        const float g = acc[m][n][q];
        float sq = (gi == gj) ? 0.f : (xi + ldsX[128 + jc] - 2.f * g);
        sq = fmaxf(sq, 0.f) + 1e-12f;
        const float dd = __builtin_amdgcn_sqrtf(sq);
        if (gj == gi + NHALF && gi < NHALF) ap[gi] = dd;  // anchor-positive distance
        const float e = __expf(MARGIN - dd);
        const uint32_t mk1 = (m1w >> (n * 16 + cl)) & 1u;
        rp += mk1 ? e : 0.f;
        const uint32_t m2bits = (m < 2) ? m2[n].x : m2[n].y;
        const uint32_t mk2 = (m2bits >> ((m & 1) * 16 + kh * 4 + q)) & 1u;
        cs[n] += mk2 ? e : 0.f;
      }
      #pragma unroll
      for (int s = 1; s < 16; s <<= 1) rp += __shfl_xor(rp, s);
      if (cl == 0) part[wc * 128 + lrow] = rp;
    }
  }

  #pragma unroll
  for (int n = 0; n < 2; ++n) {
    cs[n] += __shfl_xor(cs[n], 16);   // reduce over kh
    cs[n] += __shfl_xor(cs[n], 32);
    if (l < 16) part2[wr * 128 + wc * 32 + n * 16 + l] = cs[n];
  }
  __syncthreads();

  if (t < 128) {
    atomicAdd(&rs[brow + t],
              (part[t] + part[128 + t]) + (part[256 + t] + part[384 + t]));
    if (!diag)
      atomicAdd(&rs[bcol + t], part2[t] + part2[128 + t]);
  }
}

// ---------------- finalize: j = log(rs[i]+rs[i+N]) + ap[i]; loss ----------------
__global__ __launch_bounds__(1024) void smv2_finalize(
    const float* __restrict__ rs, const float* __restrict__ ap,
    float* __restrict__ out)
{
  const int t = threadIdx.x;
  float sum = 0.f, cnt = 0.f;
  for (int i = t; i < NHALF; i += 1024) {
    float rsum = rs[i] + rs[i + NHALF];
    float jv = logf(rsum) + ap[i];
    if (!isnan(jv)) {
      cnt += 1.f;
      float mj = fmaxf(jv, 0.f);
      sum += mj * mj;
    }
  }
  __shared__ float ssum[16], scnt[16];
  #pragma unroll
  for (int s = 32; s >= 1; s >>= 1) {
    sum += __shfl_down(sum, s);
    cnt += __shfl_down(cnt, s);
  }
  const int wid = t >> 6, lid = t & 63;
  if (lid == 0) { ssum[wid] = sum; scnt[wid] = cnt; }
  __syncthreads();
  if (t == 0) {
    float S = 0.f, C = 0.f;
    #pragma unroll
    for (int i = 0; i < 16; ++i) { S += ssum[i]; C += scnt[i]; }
    if (C < 1.f) C = 1.f;
    out[0] = S / C * 0.5f;
  }
}

extern "C" void kernel_launch(void* const* d_in, const int* in_sizes, int n_in,
                              void* d_out, int out_size, void* d_ws, size_t ws_size,
                              hipStream_t stream) {
  const float* emb = (const float*)d_in[0];
  const void* mask = d_in[1];
  char* ws = (char*)d_ws;

  ushort*   emb_bf = (ushort*)(ws + OFF_EMB);
  float*    x2     = (float*)(ws + OFF_X2);
  float*    ap     = (float*)(ws + OFF_AP);
  int*      flag   = (int*)(ws + OFF_FLAG);
  uint32_t* bitM   = (uint32_t*)(ws + OFF_BITM);
  float*    rs     = (float*)(ws + OFF_RS);

  smv2_prep<<<1024, 256, 0, stream>>>(emb, (const uint32_t*)mask, emb_bf, x2, flag);
  smv2_pack<<<2048, 256, 0, stream>>>((const uint8_t*)mask, flag, bitM, rs);
  smv2_main<<<NTRI, 512, 0, stream>>>(emb_bf, x2, (const uint8_t*)bitM, ap, rs);
  smv2_finalize<<<1, 1024, 0, stream>>>(rs, ap, (float*)d_out);
}

// Round 10
// 478.362 us; speedup vs baseline: 1.0249x; 1.0249x over previous
//
#include <hip/hip_runtime.h>
#include <hip/hip_bf16.h>
#include <stdint.h>

#define TWO_N  8192
#define NHALF  4096
#define DDIM   256
#define MARGIN 0.5f

// ---- workspace layout (bytes) ----
static const size_t OFF_EMB  = 0;                             // 8192*256 bf16 = 4 MB
static const size_t OFF_X2   = 4u * 1024 * 1024;              // 8192 f32 = 32 KB
static const size_t OFF_AP   = OFF_X2 + (size_t)TWO_N * 4;    // 4096 f32 = 16 KB
static const size_t OFF_FLAG = OFF_AP + (size_t)NHALF * 4;    // 1 int (padded)
static const size_t OFF_BITM = 5u * 1024 * 1024;              // 8192*1024 B = 8 MB bitmask
static const size_t OFF_RS   = 13u * 1024 * 1024;             // 8192 f32 = 32 KB

typedef __attribute__((ext_vector_type(8))) short bf16x8;
typedef __attribute__((ext_vector_type(4))) float f32x4;

__device__ inline ushort f2bf(float f) {
  uint32_t u = __float_as_uint(f);
  uint32_t r = (u + 0x7FFFu + ((u >> 16) & 1u)) >> 16;  // RNE
  return (ushort)r;
}
__device__ inline float bf2f(ushort h) { return __uint_as_float((uint32_t)h << 16); }

// async global->LDS, 16B per lane; HW writes LDS at uniform_base + lane*16 —
// every call below keeps per-instruction LDS spans wave-contiguous (dl = base + l*16).
__device__ inline void gload_lds16(const void* g, void* l) {
  __builtin_amdgcn_global_load_lds(
      (const __attribute__((address_space(1))) uint32_t*)(uintptr_t)g,
      (__attribute__((address_space(3))) uint32_t*)(uint32_t)(uintptr_t)l,
      16, 0, 0);
}

#define STR2(x) #x
#define WAITVM(N) asm volatile("s_waitcnt vmcnt(" STR2(N) ")" ::: "memory")

// ---------------- prep: bf16 convert + x2 (from bf16 values) + mask-dtype detect ----------------
__global__ __launch_bounds__(256) void smv2_prep(
    const float* __restrict__ emb,
    const uint32_t* __restrict__ maskw,
    ushort* __restrict__ emb_bf,
    float* __restrict__ x2,
    int* __restrict__ flag)
{
  const int t = threadIdx.x;
  if (blockIdx.x == 0) {
    __shared__ int sflag;
    if (t == 0) sflag = 0;
    __syncthreads();
    int found = 0;
    #pragma unroll
    for (int k = 0; k < 8; ++k) {
      uint32_t w = maskw[t * 8 + k];
      if (w > 1u && (w & 0xFEFEFEFEu) == 0u) found = 1;  // bytes in {0,1} => byte mask
    }
    if (found) atomicOr(&sflag, 1);
    __syncthreads();
    if (t == 0) *flag = sflag;
  }
  const int row  = blockIdx.x * 8 + (t >> 5);
  const int lane = t & 31;
  const float* rp = emb + (size_t)row * DDIM + lane * 8;
  float4 v0 = *(const float4*)(rp);
  float4 v1 = *(const float4*)(rp + 4);
  float vals[8] = {v0.x, v0.y, v0.z, v0.w, v1.x, v1.y, v1.z, v1.w};
  uint32_t packed[4];
  float ss = 0.f;
  #pragma unroll
  for (int k = 0; k < 4; ++k) {
    ushort h0 = f2bf(vals[2 * k]);
    ushort h1 = f2bf(vals[2 * k + 1]);
    packed[k] = (uint32_t)h0 | ((uint32_t)h1 << 16);
    float f0 = bf2f(h0), f1 = bf2f(h1);
    ss += f0 * f0 + f1 * f1;
  }
  *(uint4*)(emb_bf + (size_t)row * DDIM + lane * 8) =
      make_uint4(packed[0], packed[1], packed[2], packed[3]);
  #pragma unroll
  for (int m = 1; m < 32; m <<= 1) ss += __shfl_xor(ss, m);
  if (lane == 0) x2[row] = ss;
}

// ---------------- pack: mask (byte or word) -> bit mask (8192 rows x 1024 B) ----------------
__global__ __launch_bounds__(256) void smv2_pack(
    const uint8_t* __restrict__ mask8,
    const int* __restrict__ flagp,
    uint32_t* __restrict__ bitM)
{
  const int t = threadIdx.x;
  const int tid = blockIdx.x * 256 + t;
  const int isByte = *flagp;
  if (isByte) {
    #pragma unroll
    for (int it = 0; it < 4; ++it) {
      const int idx = it * (2048 * 256) + tid;   // u32 output index; 32 mask bytes
      const uint4 a = ((const uint4*)mask8)[(size_t)idx * 2];
      const uint4 b = ((const uint4*)mask8)[(size_t)idx * 2 + 1];
      const uint32_t wsv[8] = {a.x, a.y, a.z, a.w, b.x, b.y, b.z, b.w};
      uint32_t out = 0;
      #pragma unroll
      for (int j = 0; j < 8; ++j)
        out |= ((((wsv[j] & 0x01010101u) * 0x01020408u) >> 24) & 0xFu) << (4 * j);
      bitM[idx] = out;
    }
  } else {
    const uint32_t* maskw = (const uint32_t*)mask8;
    #pragma unroll
    for (int it = 0; it < 4; ++it) {
      const int idx = it * (2048 * 256) + tid;   // 32 mask words
      uint32_t out = 0;
      #pragma unroll
      for (int j = 0; j < 8; ++j) {
        const uint4 wv = ((const uint4*)maskw)[(size_t)idx * 8 + j];
        out |= (wv.x != 0u ? 1u : 0u) << (4 * j);
        out |= (wv.y != 0u ? 1u : 0u) << (4 * j + 1);
        out |= (wv.z != 0u ? 1u : 0u) << (4 * j + 2);
        out |= (wv.w != 0u ? 1u : 0u) << (4 * j + 3);
      }
      bitM[idx] = out;
    }
  }
}

// ---------------- main: row-panel streaming fused Gram -> dist -> exp -> masked row sums --------
// 256 blocks x 32 rows; 512 threads (8 waves: wr2 = row-half 0..1, wcb = col-quarter 0..3).
// A panel in registers (8 x bf16x8/thread). x2 (32 KB) + 32-row bitmask panel (32 KB) in LDS.
// Stream 8192 cols in 128 steps of 64: B-tile 32 KB double-buffered, counted vmcnt(4) +
// raw s_barrier (1-deep prefetch, queue never drained mid-loop). Per-step fused epilogue
// accumulates exp(margin-d)*mask into per-thread rsum[4]; rs written directly (no atomics).
// ALL gload_lds16 spans are wave-contiguous: dl = wave_base + i*1024 + lane*16 (rule #21).
__global__ __launch_bounds__(512, 4) void smv2_main(
    const ushort* __restrict__ emb_bf,
    const float* __restrict__ x2,
    const uint32_t* __restrict__ bitM,
    float* __restrict__ ap,
    float* __restrict__ rs)
{
  __shared__ char bufB[2][32768];      // 64 KB: col-tile double buffer (64 rows x 512 B)
  __shared__ uint32_t ldsM[32 * 256];  // 32 KB: 32-row bitmask panel
  __shared__ float ldsX[TWO_N];        // 32 KB: full x2
  __shared__ float pRed[2][16][4];     // cross-wave row-sum partials

  const int t = threadIdx.x;
  const int brow = blockIdx.x * 32;

  const int w   = t >> 6;
  const int l   = t & 63;
  const int wr2 = w >> 2;          // 0..1: 16-row half
  const int wcb = w & 3;           // 0..3: 16-col quarter of the 64-col step
  const int cl  = l & 15;
  const int kh  = l >> 4;

  // ---- staging geometry: instruction i covers LDS [w*4096 + i*1024, +1024), lane*16 inside.
  //      B-tile source is XOR-pre-swizzled (row = dl>>9, col = dl&511). ----
  const int srowb = w * 8 + (l >> 5);      // B row for i=0 (rows step +2 per i)
  const int scolb = (l & 31) * 16;         // B col byte
  const int wl16  = w * 4096 + l * 16;     // dl for i=0

#define STAGEP(GP, BUFI)                                                    \
  {                                                                         \
    _Pragma("unroll")                                                       \
    for (int i_ = 0; i_ < 4; ++i_) {                                        \
      const int row_ = srowb + i_ * 2;                                      \
      gload_lds16((GP) + (size_t)row_ * 512 + (scolb ^ ((row_ & 7) << 4)),  \
                  bufB[BUFI] + wl16 + i_ * 1024);                           \
    }                                                                       \
  }

  // ---- A fragments to registers: row = brow + wr2*16 + cl; byte ks*64 + kh*16 ----
  const char* pA = (const char*)emb_bf + (size_t)(brow + wr2 * 16 + cl) * 512 + kh * 16;
  bf16x8 afr[8];
  #pragma unroll
  for (int ks = 0; ks < 8; ++ks) afr[ks] = *(const bf16x8*)(pA + (size_t)ks * 64);

  // ---- prologue LDS issues: M (32 KB linear), X (32 KB linear), stage 0 ----
  #pragma unroll
  for (int i = 0; i < 4; ++i)
    gload_lds16((const char*)bitM + (size_t)brow * 1024 + wl16 + i * 1024,
                (char*)ldsM + wl16 + i * 1024);
  #pragma unroll
  for (int i = 0; i < 4; ++i)
    gload_lds16((const char*)x2 + wl16 + i * 1024, (char*)ldsX + wl16 + i * 1024);
  STAGEP((const char*)emb_bf, 0);

  const int bswz = (cl & 7) << 4;
  const int brow512 = (wcb * 16 + cl) * 512;

#define COMPUTE(BUFI, ACC)                                                  \
  {                                                                         \
    const char* bb = bufB[BUFI] + brow512;                                  \
    f32x4 a_ = {0.f, 0.f, 0.f, 0.f};                                        \
    _Pragma("unroll")                                                       \
    for (int ks = 0; ks < 8; ++ks) {                                        \
      bf16x8 bfr = *(const bf16x8*)(bb + (((ks * 64) | (kh * 16)) ^ bswz)); \
      a_ = __builtin_amdgcn_mfma_f32_16x16x32_bf16(afr[ks], bfr, a_, 0, 0, 0); \
    }                                                                       \
    ACC = a_;                                                               \
  }

  float rsum0 = 0.f, rsum1 = 0.f, rsum2 = 0.f, rsum3 = 0.f;
  float xi0, xi1, xi2, xi3;
  const int rl0 = wr2 * 16 + kh * 4;     // local row of q=0

#define EPI(ACC, COLG)                                                      \
  {                                                                         \
    const float xj = ldsX[COLG];                                            \
    _Pragma("unroll")                                                       \
    for (int q = 0; q < 4; ++q) {                                           \
      const int rg = brow + rl0 + q;                                        \
      const float xiq = (q == 0) ? xi0 : (q == 1) ? xi1 : (q == 2) ? xi2 : xi3; \
      const float g = (ACC)[q];                                             \
      float sq = (rg == (COLG)) ? 0.f : (xiq + xj - 2.f * g);               \
      sq = fmaxf(sq, 0.f) + 1e-12f;                                         \
      const float dd = __builtin_amdgcn_sqrtf(sq);                          \
      if ((COLG) == rg + NHALF) ap[rg] = dd;                                \
      const uint32_t mk = (ldsM[(rl0 + q) * 256 + ((COLG) >> 5)] >> ((COLG) & 31)) & 1u; \
      const float e = mk ? __expf(MARGIN - dd) : 0.f;                       \
      if (q == 0) rsum0 += e; else if (q == 1) rsum1 += e;                  \
      else if (q == 2) rsum2 += e; else rsum3 += e;                         \
    }                                                                       \
  }

  f32x4 acc;
  const char* gNext = (const char*)emb_bf + 32768;   // step-1 source
  int colg = wcb * 16 + cl;                          // step-0 column

  // ---- step 0 ----
  STAGEP(gNext, 1); gNext += 32768;
  __builtin_amdgcn_sched_barrier(0);
  WAITVM(4);                        // drains afr/M/X/stage0; leaves stage1 in flight
  __builtin_amdgcn_s_barrier();
  __builtin_amdgcn_sched_barrier(0);
  xi0 = ldsX[brow + rl0 + 0]; xi1 = ldsX[brow + rl0 + 1];
  xi2 = ldsX[brow + rl0 + 2]; xi3 = ldsX[brow + rl0 + 3];
  COMPUTE(0, acc);
  EPI(acc, colg);
  colg += 64;

  // ---- steps 1..126 (63 iterations x 2, static buffer parity) ----
  for (int it = 0; it < 63; ++it) {
    // odd step: compute buf1, stage next -> buf0
    STAGEP(gNext, 0); gNext += 32768;
    __builtin_amdgcn_sched_barrier(0);
    WAITVM(4);
    __builtin_amdgcn_s_barrier();
    __builtin_amdgcn_sched_barrier(0);
    COMPUTE(1, acc);
    EPI(acc, colg);
    colg += 64;
    // even step: compute buf0, stage next -> buf1
    STAGEP(gNext, 1); gNext += 32768;
    __builtin_amdgcn_sched_barrier(0);
    WAITVM(4);
    __builtin_amdgcn_s_barrier();
    __builtin_amdgcn_sched_barrier(0);
    COMPUTE(0, acc);
    EPI(acc, colg);
    colg += 64;
  }

  // ---- step 127 (odd -> buf1), no further stage ----
  WAITVM(0);
  __builtin_amdgcn_s_barrier();
  __builtin_amdgcn_sched_barrier(0);
  COMPUTE(1, acc);
  EPI(acc, colg);

  // ---- reduce rsum over the 16 cl-lanes, then across the 4 col-quarter waves ----
  #pragma unroll
  for (int s = 1; s < 16; s <<= 1) {
    rsum0 += __shfl_xor(rsum0, s);
    rsum1 += __shfl_xor(rsum1, s);
    rsum2 += __shfl_xor(rsum2, s);
    rsum3 += __shfl_xor(rsum3, s);
  }
  if (cl == 0) {
    pRed[wr2][kh * 4 + 0][wcb] = rsum0;
    pRed[wr2][kh * 4 + 1][wcb] = rsum1;
    pRed[wr2][kh * 4 + 2][wcb] = rsum2;
    pRed[wr2][kh * 4 + 3][wcb] = rsum3;
  }
  __syncthreads();
  if (t < 32) {
    const float* p = pRed[t >> 4][t & 15];
    rs[brow + t] = (p[0] + p[1]) + (p[2] + p[3]);
  }
#undef EPI
#undef COMPUTE
#undef STAGEP
}

// ---------------- finalize: j = log(rs[i]+rs[i+N]) + ap[i]; loss ----------------
__global__ __launch_bounds__(1024) void smv2_finalize(
    const float* __restrict__ rs, const float* __restrict__ ap,
    float* __restrict__ out)
{
  const int t = threadIdx.x;
  float sum = 0.f, cnt = 0.f;
  for (int i = t; i < NHALF; i += 1024) {
    float rsum = rs[i] + rs[i + NHALF];
    float jv = logf(rsum) + ap[i];
    if (!isnan(jv)) {
      cnt += 1.f;
      float mj = fmaxf(jv, 0.f);
      sum += mj * mj;
    }
  }
  __shared__ float ssum[16], scnt[16];
  #pragma unroll
  for (int s = 32; s >= 1; s >>= 1) {
    sum += __shfl_down(sum, s);
    cnt += __shfl_down(cnt, s);
  }
  const int wid = t >> 6, lid = t & 63;
  if (lid == 0) { ssum[wid] = sum; scnt[wid] = cnt; }
  __syncthreads();
  if (t == 0) {
    float S = 0.f, C = 0.f;
    #pragma unroll
    for (int i = 0; i < 16; ++i) { S += ssum[i]; C += scnt[i]; }
    if (C < 1.f) C = 1.f;
    out[0] = S / C * 0.5f;
  }
}

extern "C" void kernel_launch(void* const* d_in, const int* in_sizes, int n_in,
                              void* d_out, int out_size, void* d_ws, size_t ws_size,
                              hipStream_t stream) {
  const float* emb = (const float*)d_in[0];
  const void* mask = d_in[1];
  char* ws = (char*)d_ws;

  ushort*   emb_bf = (ushort*)(ws + OFF_EMB);
  float*    x2     = (float*)(ws + OFF_X2);
  float*    ap     = (float*)(ws + OFF_AP);
  int*      flag   = (int*)(ws + OFF_FLAG);
  uint32_t* bitM   = (uint32_t*)(ws + OFF_BITM);
  float*    rs     = (float*)(ws + OFF_RS);

  smv2_prep<<<1024, 256, 0, stream>>>(emb, (const uint32_t*)mask, emb_bf, x2, flag);
  smv2_pack<<<2048, 256, 0, stream>>>((const uint8_t*)mask, flag, bitM);
  smv2_main<<<256, 512, 0, stream>>>(emb_bf, x2, bitM, ap, rs);
  smv2_finalize<<<1, 1024, 0, stream>>>(rs, ap, (float*)d_out);
}

// Round 11
// 425.502 us; speedup vs baseline: 1.1523x; 1.1242x over previous
//
#include <hip/hip_runtime.h>
#include <hip/hip_bf16.h>
#include <stdint.h>

#define TWO_N  8192
#define NHALF  4096
#define DDIM   256
#define MARGIN 0.5f
#define NTRI   2080   // 64*65/2 upper-triangle tile pairs

// ---- workspace layout (bytes) ----
static const size_t OFF_EMB  = 0;                             // 8192*256 bf16 = 4 MB
static const size_t OFF_X2   = 4u * 1024 * 1024;              // 8192 f32 = 32 KB
static const size_t OFF_AP   = OFF_X2 + (size_t)TWO_N * 4;    // 4096 f32 = 16 KB
static const size_t OFF_FLAG = OFF_AP + (size_t)NHALF * 4;    // 1 int (padded)
static const size_t OFF_BITM = 5u * 1024 * 1024;              // 8192*1024 B = 8 MB bitmask
static const size_t OFF_RS   = 13u * 1024 * 1024;             // 8192 f32 = 32 KB

typedef __attribute__((ext_vector_type(8))) short bf16x8;
typedef __attribute__((ext_vector_type(4))) float f32x4;

__device__ inline ushort f2bf(float f) {
  uint32_t u = __float_as_uint(f);
  uint32_t r = (u + 0x7FFFu + ((u >> 16) & 1u)) >> 16;  // RNE
  return (ushort)r;
}
__device__ inline float bf2f(ushort h) { return __uint_as_float((uint32_t)h << 16); }

// async global->LDS; LDS dest = wave-uniform base + lane*size (rule #21)
__device__ inline void gload_lds16(const void* g, void* l) {
  __builtin_amdgcn_global_load_lds(
      (const __attribute__((address_space(1))) uint32_t*)(uintptr_t)g,
      (__attribute__((address_space(3))) uint32_t*)(uint32_t)(uintptr_t)l,
      16, 0, 0);
}
__device__ inline void gload_lds4(const void* g, void* l) {
  __builtin_amdgcn_global_load_lds(
      (const __attribute__((address_space(1))) uint32_t*)(uintptr_t)g,
      (__attribute__((address_space(3))) uint32_t*)(uint32_t)(uintptr_t)l,
      4, 0, 0);
}

#define STR2(x) #x
#define WAITVM(N) asm volatile("s_waitcnt vmcnt(" STR2(N) ")" ::: "memory")

// ---------------- prep: bf16 convert + x2 (from bf16 values) + mask-dtype detect ----------------
__global__ __launch_bounds__(256) void smv2_prep(
    const float* __restrict__ emb,
    const uint32_t* __restrict__ maskw,
    ushort* __restrict__ emb_bf,
    float* __restrict__ x2,
    int* __restrict__ flag)
{
  const int t = threadIdx.x;
  if (blockIdx.x == 0) {
    __shared__ int sflag;
    if (t == 0) sflag = 0;
    __syncthreads();
    int found = 0;
    #pragma unroll
    for (int k = 0; k < 8; ++k) {
      uint32_t w = maskw[t * 8 + k];
      if (w > 1u && (w & 0xFEFEFEFEu) == 0u) found = 1;  // bytes in {0,1} => byte mask
    }
    if (found) atomicOr(&sflag, 1);
    __syncthreads();
    if (t == 0) *flag = sflag;
  }
  const int row  = blockIdx.x * 8 + (t >> 5);
  const int lane = t & 31;
  const float* rp = emb + (size_t)row * DDIM + lane * 8;
  float4 v0 = *(const float4*)(rp);
  float4 v1 = *(const float4*)(rp + 4);
  float vals[8] = {v0.x, v0.y, v0.z, v0.w, v1.x, v1.y, v1.z, v1.w};
  uint32_t packed[4];
  float ss = 0.f;
  #pragma unroll
  for (int k = 0; k < 4; ++k) {
    ushort h0 = f2bf(vals[2 * k]);
    ushort h1 = f2bf(vals[2 * k + 1]);
    packed[k] = (uint32_t)h0 | ((uint32_t)h1 << 16);
    float f0 = bf2f(h0), f1 = bf2f(h1);
    ss += f0 * f0 + f1 * f1;
  }
  *(uint4*)(emb_bf + (size_t)row * DDIM + lane * 8) =
      make_uint4(packed[0], packed[1], packed[2], packed[3]);
  #pragma unroll
  for (int m = 1; m < 32; m <<= 1) ss += __shfl_xor(ss, m);
  if (lane == 0) x2[row] = ss;
}

// ---------------- pack: mask (byte or word) -> bit mask (8192 rows x 1024 B); zero rs ----------
__global__ __launch_bounds__(256) void smv2_pack(
    const uint8_t* __restrict__ mask8,
    const int* __restrict__ flagp,
    uint32_t* __restrict__ bitM,
    float* __restrict__ rs)
{
  const int t = threadIdx.x;
  if (blockIdx.x == 0) {            // zero rs: 8192 f32 = 2048 float4
    float4 z = {0.f, 0.f, 0.f, 0.f};
    #pragma unroll
    for (int i = 0; i < 8; ++i) ((float4*)rs)[t * 8 + i] = z;
  }
  const int tid = blockIdx.x * 256 + t;
  const int isByte = *flagp;
  if (isByte) {
    #pragma unroll
    for (int it = 0; it < 4; ++it) {
      const int idx = it * (2048 * 256) + tid;   // u32 output index; 32 mask bytes
      const uint4 a = ((const uint4*)mask8)[(size_t)idx * 2];
      const uint4 b = ((const uint4*)mask8)[(size_t)idx * 2 + 1];
      const uint32_t wsv[8] = {a.x, a.y, a.z, a.w, b.x, b.y, b.z, b.w};
      uint32_t out = 0;
      #pragma unroll
      for (int j = 0; j < 8; ++j)
        out |= ((((wsv[j] & 0x01010101u) * 0x01020408u) >> 24) & 0xFu) << (4 * j);
      bitM[idx] = out;
    }
  } else {
    const uint32_t* maskw = (const uint32_t*)mask8;
    #pragma unroll
    for (int it = 0; it < 4; ++it) {
      const int idx = it * (2048 * 256) + tid;   // 32 mask words
      uint32_t out = 0;
      #pragma unroll
      for (int j = 0; j < 8; ++j) {
        const uint4 wv = ((const uint4*)maskw)[(size_t)idx * 8 + j];
        out |= (wv.x != 0u ? 1u : 0u) << (4 * j);
        out |= (wv.y != 0u ? 1u : 0u) << (4 * j + 1);
        out |= (wv.z != 0u ? 1u : 0u) << (4 * j + 2);
        out |= (wv.w != 0u ? 1u : 0u) << (4 * j + 3);
      }
      bitM[idx] = out;
    }
  }
}

// ---------------- main: symmetric fused Gram -> dist -> exp -> masked row+col partials ----------
// R7 structure (best measured) + counted-vmcnt phases at UNCHANGED occupancy:
// upper-triangle tile pairs (by<=bx), 512 threads (8 waves 2x4), tile 128x128,
// 8 K-phases of 32, double-buffered A/B (16K+16K), bitmask M1 2K + M2 regs, x2 1K.
// Phase: WAITVM(2) -> s_barrier -> COMPUTE(p) -> s_barrier -> STAGE(p+2).
// Stage(p+2) writes the buffer compute(p) just finished reading (barrier-protected),
// and is not waited until phase p+2 — one full phase of load flight time.
// LDS 35 KB -> 4 blocks/CU.
__global__ __launch_bounds__(512, 8) void smv2_main(
    const ushort* __restrict__ emb_bf,
    const float* __restrict__ x2,
    const uint8_t* __restrict__ bitM,
    float* __restrict__ ap,
    float* __restrict__ rs)
{
  __shared__ char bufA[2 * 8192];
  __shared__ char bufB[2 * 8192];
  __shared__ uint32_t ldsM[512];       // 128 rows x 16 B bit-mask tile
  __shared__ float ldsX[256];          // x2[brow..+128) | x2[bcol..+128)

  const int t = threadIdx.x;

  // XCD chunking (2080 = 8*260) + triangular decode (bx-outer: B panel stable per XCD)
  const int bid = blockIdx.x;
  const int idx = (bid & 7) * (NTRI / 8) + (bid >> 3);
  float rf = sqrtf(8.f * (float)idx + 1.f);
  int bx = (int)((rf - 1.f) * 0.5f);
  while ((bx + 1) * (bx + 2) / 2 <= idx) ++bx;
  while (bx * (bx + 1) / 2 > idx) --bx;
  const int by = idx - bx * (bx + 1) / 2;  // by <= bx
  const int brow = by * 128;
  const int bcol = bx * 128;
  const bool diag = (bx == by);

  const char* gA = (const char*)(emb_bf + (size_t)brow * DDIM);  // 512B rows
  const char* gB = (const char*)(emb_bf + (size_t)bcol * DDIM);

  // ---- hoisted staging addresses (phase adds +64 on the global side) ----
  const int srow = t >> 2;                                      // 0..127
  const int scb  = ((t & 3) * 16) ^ (((srow >> 1) & 3) << 4);   // pre-swizzled col
  const size_t gOff = (size_t)srow * 512 + scb;
  const int ldst = t * 16;

  const int w  = t >> 6;
  const int l  = t & 63;
  const int wr = w >> 2;           // wave row 0..1  (64 rows)
  const int wc = w & 3;            // wave col 0..3  (32 cols)
  const int cl = l & 15;
  const int kh = l >> 4;

  // ---- hoisted ds_read offsets (bank-swizzled: ((row>>1)&3)<<4 on 64B rows) ----
  int aoff[4], boff[2];
  #pragma unroll
  for (int m = 0; m < 4; ++m) {
    const int row = wr * 64 + m * 16 + cl;
    aoff[m] = row * 64 + ((kh * 16) ^ (((row >> 1) & 3) << 4));
  }
  #pragma unroll
  for (int n = 0; n < 2; ++n) {
    const int row = wc * 32 + n * 16 + cl;
    boff[n] = row * 64 + ((kh * 16) ^ (((row >> 1) & 3) << 4));
  }

  f32x4 acc[4][2];
  #pragma unroll
  for (int m = 0; m < 4; ++m)
    #pragma unroll
    for (int n = 0; n < 2; ++n) {
      f32x4 z = {0.f, 0.f, 0.f, 0.f};
      acc[m][n] = z;
    }

  // ---- prologue VMEM issue (queue: M2·2, M1, X, S0·2, S1·2 = 8) ----
  uint2 m2[2];
  #pragma unroll
  for (int n = 0; n < 2; ++n) {
    const int gj = bcol + wc * 32 + n * 16 + cl;
    m2[n] = *(const uint2*)((const uint32_t*)bitM + (size_t)gj * 256 + (brow >> 5) + wr * 2);
  }
  gload_lds4(bitM + (size_t)(brow + srow) * 1024 + (bcol >> 3) + (t & 3) * 4,
             (char*)ldsM + t * 4);
  {
    const int xi = t & 255;
    const float* src = (xi < 128) ? (x2 + brow + xi) : (x2 + bcol + (xi - 128));
    gload_lds4(src, (char*)ldsX + xi * 4);
  }

#define STAGE(Q)                                                            \
  {                                                                         \
    gload_lds16(gA + gOff + (Q) * 64, bufA + ((Q) & 1) * 8192 + ldst);      \
    gload_lds16(gB + gOff + (Q) * 64, bufB + ((Q) & 1) * 8192 + ldst);      \
  }

  STAGE(0);
  STAGE(1);

#define COMPUTE(P)                                                          \
  {                                                                         \
    const char* ba = bufA + ((P) & 1) * 8192;                               \
    const char* bb = bufB + ((P) & 1) * 8192;                               \
    bf16x8 a0 = *(const bf16x8*)(ba + aoff[0]);                             \
    bf16x8 a1 = *(const bf16x8*)(ba + aoff[1]);                             \
    bf16x8 a2 = *(const bf16x8*)(ba + aoff[2]);                             \
    bf16x8 a3 = *(const bf16x8*)(ba + aoff[3]);                             \
    bf16x8 b0 = *(const bf16x8*)(bb + boff[0]);                             \
    bf16x8 b1 = *(const bf16x8*)(bb + boff[1]);                             \
    acc[0][0] = __builtin_amdgcn_mfma_f32_16x16x32_bf16(a0, b0, acc[0][0], 0, 0, 0); \
    acc[0][1] = __builtin_amdgcn_mfma_f32_16x16x32_bf16(a0, b1, acc[0][1], 0, 0, 0); \
    acc[1][0] = __builtin_amdgcn_mfma_f32_16x16x32_bf16(a1, b0, acc[1][0], 0, 0, 0); \
    acc[1][1] = __builtin_amdgcn_mfma_f32_16x16x32_bf16(a1, b1, acc[1][1], 0, 0, 0); \
    acc[2][0] = __builtin_amdgcn_mfma_f32_16x16x32_bf16(a2, b0, acc[2][0], 0, 0, 0); \
    acc[2][1] = __builtin_amdgcn_mfma_f32_16x16x32_bf16(a2, b1, acc[2][1], 0, 0, 0); \
    acc[3][0] = __builtin_amdgcn_mfma_f32_16x16x32_bf16(a3, b0, acc[3][0], 0, 0, 0); \
    acc[3][1] = __builtin_amdgcn_mfma_f32_16x16x32_bf16(a3, b1, acc[3][1], 0, 0, 0); \
  }

// counted-vmcnt phase: wait for S(P) (leave S(P+1) in flight), compute, then
// after the reads-done barrier stage S(P+2) into the buffer just read.
#define PHASE(P, NW)                                                        \
  {                                                                         \
    WAITVM(NW);                                                             \
    __builtin_amdgcn_s_barrier();                                           \
    __builtin_amdgcn_sched_barrier(0);                                      \
    COMPUTE(P);                                                             \
    __builtin_amdgcn_s_barrier();                                           \
    __builtin_amdgcn_sched_barrier(0);                                      \
    if ((P) < 6) STAGE((P) + 2);                                            \
  }

  PHASE(0, 2) PHASE(1, 2) PHASE(2, 2) PHASE(3, 2)
  PHASE(4, 2) PHASE(5, 2) PHASE(6, 2) PHASE(7, 0)

  // ---- epilogue (M1/X drained at phase-0 wait; M2 regs likewise) ----
  float* part  = (float*)bufA;   // 2 KB in buf0 region; compute(7) read buf1 — disjoint
  float* part2 = (float*)bufB;   // 1 KB in buf0 region of B
  float cs[2] = {0.f, 0.f};

  #pragma unroll
  for (int m = 0; m < 4; ++m) {
    #pragma unroll
    for (int q = 0; q < 4; ++q) {
      const int lrow = wr * 64 + m * 16 + kh * 4 + q;  // C/D: row = (l>>4)*4 + reg
      const int gi = brow + lrow;
      const float xi = ldsX[lrow];
      const uint32_t m1w = ldsM[lrow * 4 + wc];        // bits for cols [wc*32, +32)
      float rp = 0.f;
      #pragma unroll
      for (int n = 0; n < 2; ++n) {
        const int jc = wc * 32 + n * 16 + cl;
        const int gj = bcol + jc;
        const float g = acc[m][n][q];
        float sq = (gi == gj) ? 0.f : (xi + ldsX[128 + jc] - 2.f * g);
        sq = fmaxf(sq, 0.f) + 1e-12f;
        const float dd = __builtin_amdgcn_sqrtf(sq);
        if (gj == gi + NHALF && gi < NHALF) ap[gi] = dd;  // anchor-positive distance
        const float e = __expf(MARGIN - dd);
        const uint32_t mk1 = (m1w >> (n * 16 + cl)) & 1u;
        rp += mk1 ? e : 0.f;
        const uint32_t m2bits = (m < 2) ? m2[n].x : m2[n].y;
        const uint32_t mk2 = (m2bits >> ((m & 1) * 16 + kh * 4 + q)) & 1u;
        cs[n] += mk2 ? e : 0.f;
      }
      #pragma unroll
      for (int s = 1; s < 16; s <<= 1) rp += __shfl_xor(rp, s);
      if (cl == 0) part[wc * 128 + lrow] = rp;
    }
  }

  #pragma unroll
  for (int n = 0; n < 2; ++n) {
    cs[n] += __shfl_xor(cs[n], 16);   // reduce over kh
    cs[n] += __shfl_xor(cs[n], 32);
    if (l < 16) part2[wr * 128 + wc * 32 + n * 16 + l] = cs[n];
  }
  __syncthreads();

  if (t < 128) {
    atomicAdd(&rs[brow + t],
              (part[t] + part[128 + t]) + (part[256 + t] + part[384 + t]));
    if (!diag)
      atomicAdd(&rs[bcol + t], part2[t] + part2[128 + t]);
  }
#undef PHASE
#undef COMPUTE
#undef STAGE
}

// ---------------- finalize: j = log(rs[i]+rs[i+N]) + ap[i]; loss ----------------
__global__ __launch_bounds__(1024) void smv2_finalize(
    const float* __restrict__ rs, const float* __restrict__ ap,
    float* __restrict__ out)
{
  const int t = threadIdx.x;
  float sum = 0.f, cnt = 0.f;
  for (int i = t; i < NHALF; i += 1024) {
    float rsum = rs[i] + rs[i + NHALF];
    float jv = logf(rsum) + ap[i];
    if (!isnan(jv)) {
      cnt += 1.f;
      float mj = fmaxf(jv, 0.f);
      sum += mj * mj;
    }
  }
  __shared__ float ssum[16], scnt[16];
  #pragma unroll
  for (int s = 32; s >= 1; s >>= 1) {
    sum += __shfl_down(sum, s);
    cnt += __shfl_down(cnt, s);
  }
  const int wid = t >> 6, lid = t & 63;
  if (lid == 0) { ssum[wid] = sum; scnt[wid] = cnt; }
  __syncthreads();
  if (t == 0) {
    float S = 0.f, C = 0.f;
    #pragma unroll
    for (int i = 0; i < 16; ++i) { S += ssum[i]; C += scnt[i]; }
    if (C < 1.f) C = 1.f;
    out[0] = S / C * 0.5f;
  }
}

extern "C" void kernel_launch(void* const* d_in, const int* in_sizes, int n_in,
                              void* d_out, int out_size, void* d_ws, size_t ws_size,
                              hipStream_t stream) {
  const float* emb = (const float*)d_in[0];
  const void* mask = d_in[1];
  char* ws = (char*)d_ws;

  ushort*   emb_bf = (ushort*)(ws + OFF_EMB);
  float*    x2     = (float*)(ws + OFF_X2);
  float*    ap     = (float*)(ws + OFF_AP);
  int*      flag   = (int*)(ws + OFF_FLAG);
  uint32_t* bitM   = (uint32_t*)(ws + OFF_BITM);
  float*    rs     = (float*)(ws + OFF_RS);

  smv2_prep<<<1024, 256, 0, stream>>>(emb, (const uint32_t*)mask, emb_bf, x2, flag);
  smv2_pack<<<2048, 256, 0, stream>>>((const uint8_t*)mask, flag, bitM, rs);
  smv2_main<<<NTRI, 512, 0, stream>>>(emb_bf, x2, (const uint8_t*)bitM, ap, rs);
  smv2_finalize<<<1, 1024, 0, stream>>>(rs, ap, (float*)d_out);
}